// Round 1
// baseline (1067.782 us; speedup 1.0000x reference)
//
#include <hip/hip_runtime.h>
#include <math.h>

// MoE gate: logits = x @ W^T ; softmax ; top-8 (idx, weight), sorted desc.
// x: [T, 2048] fp32, W: [64, 2048] fp32.
// Output layout (all float32): d_out[0 .. T*8)      = topk_idx (as float)
//                              d_out[T*8 .. 2*T*8)  = topk_weight

constexpr int H = 2048;
constexpr int E = 64;
constexpr int TOPK = 8;
constexpr int TOK_PER_BLK = 32;   // tokens per block
constexpr int NE_THR = 8;         // experts per thread (8 groups x 8 = 64)

__global__ __launch_bounds__(256, 2)
void moe_gate_kernel(const float* __restrict__ x, const float* __restrict__ w,
                     float* __restrict__ out, int T) {
    __shared__ float lg[TOK_PER_BLK][E + 4];   // logits; row stride 68 floats (272B, 16B-aligned)

    const int tid = threadIdx.x;
    const int eg  = tid & 7;        // expert group: experts eg*8 .. eg*8+7
    const int tl  = tid >> 3;       // local token 0..31
    const int tok = blockIdx.x * TOK_PER_BLK + tl;

    const float* __restrict__ xrow  = x + (size_t)tok * H;
    const float* __restrict__ wbase = w + (size_t)(eg * NE_THR) * H;

    float acc[NE_THR];
    #pragma unroll
    for (int j = 0; j < NE_THR; ++j) acc[j] = 0.f;

    // prefetch first x chunk (16 floats)
    float4 xv0 = *reinterpret_cast<const float4*>(xrow + 0);
    float4 xv1 = *reinterpret_cast<const float4*>(xrow + 4);
    float4 xv2 = *reinterpret_cast<const float4*>(xrow + 8);
    float4 xv3 = *reinterpret_cast<const float4*>(xrow + 12);

    for (int k0 = 0; k0 < H; k0 += 16) {
        // prefetch next x chunk while this chunk's 128 FMAs run
        float4 xn0, xn1, xn2, xn3;
        const int kn = k0 + 16;
        if (kn < H) {
            xn0 = *reinterpret_cast<const float4*>(xrow + kn + 0);
            xn1 = *reinterpret_cast<const float4*>(xrow + kn + 4);
            xn2 = *reinterpret_cast<const float4*>(xrow + kn + 8);
            xn3 = *reinterpret_cast<const float4*>(xrow + kn + 12);
        }
        #pragma unroll
        for (int j = 0; j < NE_THR; ++j) {
            const float* __restrict__ wr = wbase + (size_t)j * H + k0;
            const float4 wv0 = *reinterpret_cast<const float4*>(wr + 0);
            const float4 wv1 = *reinterpret_cast<const float4*>(wr + 4);
            const float4 wv2 = *reinterpret_cast<const float4*>(wr + 8);
            const float4 wv3 = *reinterpret_cast<const float4*>(wr + 12);
            float a = acc[j];
            a = fmaf(xv0.x, wv0.x, a); a = fmaf(xv0.y, wv0.y, a);
            a = fmaf(xv0.z, wv0.z, a); a = fmaf(xv0.w, wv0.w, a);
            a = fmaf(xv1.x, wv1.x, a); a = fmaf(xv1.y, wv1.y, a);
            a = fmaf(xv1.z, wv1.z, a); a = fmaf(xv1.w, wv1.w, a);
            a = fmaf(xv2.x, wv2.x, a); a = fmaf(xv2.y, wv2.y, a);
            a = fmaf(xv2.z, wv2.z, a); a = fmaf(xv2.w, wv2.w, a);
            a = fmaf(xv3.x, wv3.x, a); a = fmaf(xv3.y, wv3.y, a);
            a = fmaf(xv3.z, wv3.z, a); a = fmaf(xv3.w, wv3.w, a);
            acc[j] = a;
        }
        xv0 = xn0; xv1 = xn1; xv2 = xn2; xv3 = xn3;
    }

    // stash logits in LDS
    #pragma unroll
    for (int j = 0; j < NE_THR; ++j) lg[tl][eg * NE_THR + j] = acc[j];
    __syncthreads();

    // per-token softmax + top-8 (one thread per token)
    if (tid < TOK_PER_BLK) {
        const int t = blockIdx.x * TOK_PER_BLK + tid;
        float* lrow = lg[tid];

        float m = lrow[0];
        for (int i = 1; i < E; ++i) m = fmaxf(m, lrow[i]);
        float s = 0.f;
        for (int i = 0; i < E; ++i) s += expf(lrow[i] - m);

        float* __restrict__ oidx = out + (size_t)t * TOPK;
        float* __restrict__ ow   = out + (size_t)T * TOPK + (size_t)t * TOPK;

        for (int p = 0; p < TOPK; ++p) {
            float best = -INFINITY; int bi = 0;
            for (int i = 0; i < E; ++i) {
                float v = lrow[i];
                if (v > best) { best = v; bi = i; }   // strict >: ties -> lowest index
            }
            oidx[p] = (float)bi;
            ow[p]   = expf(best - m) / s;
            lrow[bi] = -INFINITY;
        }
    }
}

extern "C" void kernel_launch(void* const* d_in, const int* in_sizes, int n_in,
                              void* d_out, int out_size, void* d_ws, size_t ws_size,
                              hipStream_t stream) {
    const float* x = (const float*)d_in[0];
    const float* w = (const float*)d_in[1];
    float* out = (float*)d_out;
    const int T = in_sizes[0] / H;                 // 16384
    const int grid = (T + TOK_PER_BLK - 1) / TOK_PER_BLK;   // 512
    hipLaunchKernelGGL(moe_gate_kernel, dim3(grid), dim3(256), 0, stream,
                       x, w, out, T);
}